// Round 9
// baseline (320.554 us; speedup 1.0000x reference)
//
#include <hip/hip_runtime.h>
#include <hip/hip_bf16.h>
#include <math.h>

#define DIM 768
#define NHEAD 12
#define HD 64
#define HIDDEN 384
#define BATCH 8
#define SEQ 1024
#define ROWS (BATCH*SEQ)
#define CHUNKB 4
#define CHUNKR (CHUNKB*SEQ)

typedef short bf16x8 __attribute__((ext_vector_type(8)));
typedef float f32x4 __attribute__((ext_vector_type(4)));
typedef unsigned int u32x2 __attribute__((ext_vector_type(2)));
typedef unsigned short u16;
typedef unsigned int u32;

__device__ __forceinline__ u16 f2bs(float f) {
    unsigned int u = __float_as_uint(f);
    unsigned int r = (u + 0x7FFFu + ((u >> 16) & 1u)) >> 16;
    return (u16)r;
}

__device__ __forceinline__ u32 packbf2(float a, float b) {
    __hip_bfloat162 h = __float22bfloat162_rn(make_float2(a, b));
    u32 r;
    __builtin_memcpy(&r, &h, 4);
    return r;
}

// async global->LDS DMA, 16 B/lane; LDS dest = wave-uniform base + lane*16
__device__ __forceinline__ void gld16(const u16* g, u16* l) {
    __builtin_amdgcn_global_load_lds(
        (const __attribute__((address_space(1))) unsigned int*)g,
        (__attribute__((address_space(3))) unsigned int*)l, 16, 0, 0);
}

// ---------------- tiled weight transpose: Wt[n][k] = bf16(W[k][n]) ----------------
__global__ __launch_bounds__(256) void wtrans(const float* __restrict__ W,
                                              u16* __restrict__ Wt, int K, int N) {
    __shared__ float tile[32][33];
    int n0 = blockIdx.x * 32, k0 = blockIdx.y * 32;
    int tx = threadIdx.x & 31, ty = threadIdx.x >> 5;
#pragma unroll
    for (int i = 0; i < 4; i++)
        tile[ty + i * 8][tx] = W[(long)(k0 + ty + i * 8) * N + n0 + tx];
    __syncthreads();
#pragma unroll
    for (int i = 0; i < 4; i++)
        Wt[(long)(n0 + ty + i * 8) * K + k0 + tx] = f2bs(tile[tx][ty + i * 8]);
}

// ---------------- layernorm: fp32 in -> bf16 out, one block per row ----------------
__global__ __launch_bounds__(256) void lnorm(const float* __restrict__ X,
                                             const float* __restrict__ w,
                                             const float* __restrict__ b,
                                             u16* __restrict__ Y) {
    int row = blockIdx.x;
    const float* xr = X + (long)row * DIM;
    int t = threadIdx.x;
    float v0 = xr[t], v1 = xr[t + 256], v2 = xr[t + 512];
    float s = v0 + v1 + v2;
    float s2 = v0 * v0 + v1 * v1 + v2 * v2;
    for (int off = 1; off < 64; off <<= 1) {
        s  += __shfl_xor(s,  off, 64);
        s2 += __shfl_xor(s2, off, 64);
    }
    __shared__ float ss[4], ss2[4];
    int wid = t >> 6;
    if ((t & 63) == 0) { ss[wid] = s; ss2[wid] = s2; }
    __syncthreads();
    s  = ss[0] + ss[1] + ss[2] + ss[3];
    s2 = ss2[0] + ss2[1] + ss2[2] + ss2[3];
    float mu = s * (1.0f / DIM);
    float var = s2 * (1.0f / DIM) - mu * mu;
    float rstd = rsqrtf(var + 1e-5f);
    u16* yr = Y + (long)row * DIM;
    yr[t]       = f2bs((v0 - mu) * rstd * w[t]       + b[t]);
    yr[t + 256] = f2bs((v1 - mu) * rstd * w[t + 256] + b[t + 256]);
    yr[t + 512] = f2bs((v2 - mu) * rstd * w[t + 512] + b[t + 512]);
}

// ---------------- bf16 MFMA GEMM (R7 config: single-buffer, BK=64, gld16+swizzle) -----
template <int BM, int BN, int EPI>
__global__ __launch_bounds__(256) void gemm_bt(const u16* __restrict__ A,
                                               const u16* __restrict__ Bt,
                                               int M, int N, int K,
                                               u16* __restrict__ Cb,
                                               float* __restrict__ Cf,
                                               const float* __restrict__ resid,
                                               const float* __restrict__ bias) {
    constexpr int MB = BM / 32, NB = BN / 32;
    __shared__ u16 As[BM * 64];
    __shared__ u16 Bs[BN * 64];
    int m0 = blockIdx.y * BM;
    int n0 = blockIdx.x * BN;
    int t = threadIdx.x;
    int lane = t & 63, w = t >> 6;
    int quad = lane >> 4, l16 = lane & 15;
    int wr = w >> 1, wc = w & 1;
    int lr = lane >> 3, lc = lane & 7;
    int sc = (lc ^ lr) * 8;      // swizzled source chunk offset (u16)
    int x7 = l16 & 7;

    f32x4 acc[MB][NB];
#pragma unroll
    for (int mb = 0; mb < MB; mb++)
#pragma unroll
        for (int nb = 0; nb < NB; nb++) acc[mb][nb] = (f32x4){0.f, 0.f, 0.f, 0.f};

    for (int kt = 0; kt < K; kt += 64) {
        __syncthreads();
#pragma unroll
        for (int i = 0; i < BM / 32; i++) {
            int rb = i * 32 + w * 8;
            gld16(&A[(long)(m0 + rb + lr) * K + kt + sc], &As[rb * 64]);
        }
#pragma unroll
        for (int i = 0; i < BN / 32; i++) {
            int rb = i * 32 + w * 8;
            gld16(&Bt[(long)(n0 + rb + lr) * K + kt + sc], &Bs[rb * 64]);
        }
        __syncthreads();
#pragma unroll
        for (int kh = 0; kh < 2; kh++) {
            bf16x8 af[MB], bfr[NB];
#pragma unroll
            for (int mb = 0; mb < MB; mb++)
                af[mb] = *(const bf16x8*)&As[(wr * (BM / 2) + mb * 16 + l16) * 64 +
                                             (((kh * 4 + quad) ^ x7) * 8)];
#pragma unroll
            for (int nb = 0; nb < NB; nb++)
                bfr[nb] = *(const bf16x8*)&Bs[(wc * (BN / 2) + nb * 16 + l16) * 64 +
                                              (((kh * 4 + quad) ^ x7) * 8)];
#pragma unroll
            for (int mb = 0; mb < MB; mb++)
#pragma unroll
                for (int nb = 0; nb < NB; nb++)
                    acc[mb][nb] = __builtin_amdgcn_mfma_f32_16x16x32_bf16(af[mb], bfr[nb], acc[mb][nb], 0, 0, 0);
        }
    }

    int mbase = m0 + wr * (BM / 2), nbase = n0 + wc * (BN / 2);
#pragma unroll
    for (int mb = 0; mb < MB; mb++)
#pragma unroll
        for (int nb = 0; nb < NB; nb++) {
            int r0 = mbase + mb * 16 + quad * 4;
            int c = nbase + nb * 16 + l16;
#pragma unroll
            for (int r = 0; r < 4; r++) {
                float v = acc[mb][nb][r];
                long idx = (long)(r0 + r) * N + c;
                if (EPI == 0) {
                    Cb[idx] = f2bs(v);
                } else if (EPI == 1) {
                    Cf[idx] = resid[idx] + v;
                } else if (EPI == 2) {
                    float xg = v + bias[c];
                    Cb[idx] = f2bs(xg * 0.5f * (1.0f + erff(xg * 0.70710678118f)));
                } else {
                    Cf[idx] = resid[idx] + v + bias[c];
                }
            }
        }
}

// ---------------- flash attention: QT=128 q-rows/block, KT=128 keys/iter ----------------
// S^T formulation (per-lane softmax). All three LDS tiles XOR-swizzled + 48 KB total:
//  Ks 128x64 (chunk^(row&7))  -- fixes R7/R8 4-way K-write conflict (bank%4==0 only)
//  Ps 16x128  (chunk16^l16)   -- fixes R7/R8 4-way P-store conflict (even banks only)
//  Vs 64x128  (chunk^(d&15))  -- R8 layout, proven conflict-free
__global__ __launch_bounds__(256, 3) void attn(const u16* __restrict__ QKV, u16* __restrict__ O) {
    __shared__ u16 Ks[128 * 64];      // 16 KB
    __shared__ u16 Vs[64 * 128];      // 16 KB
    __shared__ u16 Ps[4][16 * 128];   // 16 KB (wave-private rows)
    int q0 = blockIdx.x * 128;
    int h = blockIdx.y;
    int b = blockIdx.z;
    int t = threadIdx.x;
    int lane = t & 63, w = t >> 6;
    int quad = lane >> 4, l16 = lane & 15;

    const long rs = 3 * DIM;  // 2304
    const u16* base = QKV + (long)b * SEQ * rs;

    bf16x8 qf[2][2];
#pragma unroll
    for (int rg = 0; rg < 2; rg++) {
        int qrow = q0 + w * 32 + rg * 16 + l16;
        qf[rg][0] = *(const bf16x8*)&base[(long)qrow * rs + h * 64 + quad * 8];
        qf[rg][1] = *(const bf16x8*)&base[(long)qrow * rs + h * 64 + 32 + quad * 8];
    }

    f32x4 o[2][4];
#pragma unroll
    for (int rg = 0; rg < 2; rg++)
#pragma unroll
        for (int jb = 0; jb < 4; jb++) o[rg][jb] = (f32x4){0.f, 0.f, 0.f, 0.f};
    float m_run[2] = {-1e30f, -1e30f};
    float l_run[2] = {0.f, 0.f};

    const float L2E8 = 11.54156032f;  // 8 * log2(e)

    int kvr = t >> 1;                  // K: row 0..127
    int kcb = (t & 1) * 4;             // K: chunk base (4 chunks of 8 u16 each)
    int kx7 = kvr & 7;                 // K write swizzle mask
    int vp = t & 63, vo = t >> 6;      // V: kv-pair, d-block
    int vc = vp >> 2, voff = (vp & 3) * 2;

    const u16* kptr = &base[(long)kvr * rs + DIM + h * 64 + kcb * 8];
    const u16* vptr = &base[(long)(2 * vp) * rs + 2 * DIM + h * 64 + vo * 16];
    const long kstep = (long)128 * rs;

    bf16x8 kpre[4], va0, va1, vb0, vb1;
    kpre[0] = *(const bf16x8*)&kptr[0];
    kpre[1] = *(const bf16x8*)&kptr[8];
    kpre[2] = *(const bf16x8*)&kptr[16];
    kpre[3] = *(const bf16x8*)&kptr[24];
    va0 = *(const bf16x8*)&vptr[0];
    va1 = *(const bf16x8*)&vptr[8];
    vb0 = *(const bf16x8*)&vptr[rs];
    vb1 = *(const bf16x8*)&vptr[rs + 8];

    for (int kt = 0; kt < SEQ; kt += 128) {
        __syncthreads();
        {
#pragma unroll
            for (int j = 0; j < 4; j++)
                *(bf16x8*)&Ks[kvr * 64 + (((kcb + j) ^ kx7) * 8)] = kpre[j];
#pragma unroll
            for (int j = 0; j < 8; j++) {
                int d = vo * 16 + j;
                u32 pk = (u32)(u16)va0[j] | ((u32)(u16)vb0[j] << 16);
                *(u32*)&Vs[d * 128 + ((vc ^ j) * 8) + voff] = pk;
            }
#pragma unroll
            for (int j = 0; j < 8; j++) {
                int d = vo * 16 + 8 + j;
                u32 pk = (u32)(u16)va1[j] | ((u32)(u16)vb1[j] << 16);
                *(u32*)&Vs[d * 128 + ((vc ^ (8 + j)) * 8) + voff] = pk;
            }
        }
        __syncthreads();

        if (kt + 128 < SEQ) {
            kptr += kstep; vptr += kstep;
            kpre[0] = *(const bf16x8*)&kptr[0];
            kpre[1] = *(const bf16x8*)&kptr[8];
            kpre[2] = *(const bf16x8*)&kptr[16];
            kpre[3] = *(const bf16x8*)&kptr[24];
            va0 = *(const bf16x8*)&vptr[0];
            va1 = *(const bf16x8*)&vptr[8];
            vb0 = *(const bf16x8*)&vptr[rs];
            vb1 = *(const bf16x8*)&vptr[rs + 8];
        }

#pragma unroll
        for (int rg = 0; rg < 2; rg++) {
            f32x4 s[8];
#pragma unroll
            for (int jb = 0; jb < 8; jb++) {
                int krow = jb * 16 + l16;
                int m7 = l16 & 7;   // == krow&7
                bf16x8 kf0 = *(const bf16x8*)&Ks[krow * 64 + ((quad ^ m7) * 8)];
                bf16x8 kf1 = *(const bf16x8*)&Ks[krow * 64 + (((4 + quad) ^ m7) * 8)];
                f32x4 z = (f32x4){0.f, 0.f, 0.f, 0.f};
                z = __builtin_amdgcn_mfma_f32_16x16x32_bf16(kf0, qf[rg][0], z, 0, 0, 0);
                z = __builtin_amdgcn_mfma_f32_16x16x32_bf16(kf1, qf[rg][1], z, 0, 0, 0);
                s[jb] = z;
            }

            float m1 = s[0][0];
#pragma unroll
            for (int jb = 0; jb < 8; jb++)
#pragma unroll
                for (int r = 0; r < 4; r++) m1 = fmaxf(m1, s[jb][r]);
            m1 = fmaxf(m1, __shfl_xor(m1, 16, 64));
            m1 = fmaxf(m1, __shfl_xor(m1, 32, 64));
            float mn = fmaxf(m_run[rg], m1);
            float alpha = exp2f((m_run[rg] - mn) * L2E8);
            m_run[rg] = mn;
            float mn8 = mn * L2E8;
            float rsum = 0.f;
#pragma unroll
            for (int jb = 0; jb < 8; jb++)
#pragma unroll
                for (int r = 0; r < 4; r++) {
                    float p = exp2f(fmaf(s[jb][r], L2E8, -mn8));
                    s[jb][r] = p;
                    rsum += p;
                }
            rsum += __shfl_xor(rsum, 16, 64);
            rsum += __shfl_xor(rsum, 32, 64);
            l_run[rg] = l_run[rg] * alpha + rsum;

            float a0 = __shfl(alpha, quad * 4 + 0, 16);
            float a1 = __shfl(alpha, quad * 4 + 1, 16);
            float a2 = __shfl(alpha, quad * 4 + 2, 16);
            float a3 = __shfl(alpha, quad * 4 + 3, 16);
#pragma unroll
            for (int jb = 0; jb < 4; jb++) {
                o[rg][jb][0] *= a0; o[rg][jb][1] *= a1;
                o[rg][jb][2] *= a2; o[rg][jb][3] *= a3;
            }

            // P store: value block (q=l16, kv=jb*16+quad*4+{0..3}) -> 16B-chunk
            // cw = jb*2+(quad>>1), half (quad&1); swizzled chunk = cw ^ l16.
#pragma unroll
            for (int jb = 0; jb < 8; jb++) {
                u32x2 pk;
                pk.x = packbf2(s[jb][0], s[jb][1]);
                pk.y = packbf2(s[jb][2], s[jb][3]);
                int swc = (jb * 2 + (quad >> 1)) ^ l16;
                *(u32x2*)&Ps[w][l16 * 128 + swc * 8 + (quad & 1) * 4] = pk;
            }

#pragma unroll
            for (int c = 0; c < 4; c++) {
                bf16x8 pf = *(const bf16x8*)&Ps[w][l16 * 128 + (((c * 4 + quad) ^ l16) * 8)];
#pragma unroll
                for (int jb = 0; jb < 4; jb++) {
                    int d = jb * 16 + l16;
                    bf16x8 vf = *(const bf16x8*)&Vs[d * 128 + (((c * 4 + quad) ^ l16) * 8)];
                    o[rg][jb] = __builtin_amdgcn_mfma_f32_16x16x32_bf16(pf, vf, o[rg][jb], 0, 0, 0);
                }
            }
        }
    }

#pragma unroll
    for (int rg = 0; rg < 2; rg++) {
        float l0 = __shfl(l_run[rg], quad * 4 + 0, 16);
        float l1 = __shfl(l_run[rg], quad * 4 + 1, 16);
        float l2 = __shfl(l_run[rg], quad * 4 + 2, 16);
        float l3 = __shfl(l_run[rg], quad * 4 + 3, 16);
        u16* orow = O + ((long)(b * SEQ + q0 + w * 32 + rg * 16)) * DIM + h * 64;
#pragma unroll
        for (int jb = 0; jb < 4; jb++) {
            u32 p01 = packbf2(o[rg][jb][0] / l0, o[rg][jb][1] / l1);
            u32 p23 = packbf2(o[rg][jb][2] / l2, o[rg][jb][3] / l3);
            int cidx = jb * 16 + l16;
            orow[(long)(quad * 4 + 0) * DIM + cidx] = (u16)p01;
            orow[(long)(quad * 4 + 1) * DIM + cidx] = (u16)(p01 >> 16);
            orow[(long)(quad * 4 + 2) * DIM + cidx] = (u16)p23;
            orow[(long)(quad * 4 + 3) * DIM + cidx] = (u16)(p23 >> 16);
        }
    }
}

extern "C" void kernel_launch(void* const* d_in, const int* in_sizes, int n_in,
                              void* d_out, int out_size, void* d_ws, size_t ws_size,
                              hipStream_t stream) {
    const float* x     = (const float*)d_in[0];
    const float* ln1w  = (const float*)d_in[1];
    const float* ln1b  = (const float*)d_in[2];
    const float* ln2w  = (const float*)d_in[3];
    const float* ln2b  = (const float*)d_in[4];
    const float* wqkv  = (const float*)d_in[5];
    const float* wproj = (const float*)d_in[6];
    const float* wfc1  = (const float*)d_in[7];
    const float* bfc1  = (const float*)d_in[8];
    const float* wfc2  = (const float*)d_in[9];
    const float* bfc2  = (const float*)d_in[10];
    float* out = (float*)d_out;

    char* ws = (char*)d_ws;
    size_t off = 0;
    auto alloc = [&](size_t bytes) {
        void* p = ws + off;
        off = (off + bytes + 255) & ~(size_t)255;
        return p;
    };
    u16* wt_qkv  = (u16*)alloc((size_t)3 * DIM * DIM * 2);
    u16* wt_proj = (u16*)alloc((size_t)DIM * DIM * 2);
    u16* wt_fc1  = (u16*)alloc((size_t)HIDDEN * DIM * 2);
    u16* wt_fc2  = (u16*)alloc((size_t)DIM * HIDDEN * 2);
    u16* hbuf    = (u16*)alloc((size_t)ROWS * DIM * 2);
    u16* gbuf    = (u16*)alloc((size_t)ROWS * HIDDEN * 2);
    size_t qkv_bytes = (size_t)ROWS * 3 * DIM * 2;
    u16* qkvfull = (off + qkv_bytes + 1024 <= ws_size) ? (u16*)alloc(qkv_bytes) : nullptr;

    wtrans<<<dim3(3 * DIM / 32, DIM / 32), 256, 0, stream>>>(wqkv, wt_qkv, DIM, 3 * DIM);
    wtrans<<<dim3(DIM / 32, DIM / 32), 256, 0, stream>>>(wproj, wt_proj, DIM, DIM);
    wtrans<<<dim3(HIDDEN / 32, DIM / 32), 256, 0, stream>>>(wfc1, wt_fc1, DIM, HIDDEN);
    wtrans<<<dim3(DIM / 32, HIDDEN / 32), 256, 0, stream>>>(wfc2, wt_fc2, HIDDEN, DIM);

    lnorm<<<ROWS, 256, 0, stream>>>(x, ln1w, ln1b, hbuf);

    if (qkvfull) {
        gemm_bt<128, 128, 0><<<dim3(3 * DIM / 128, ROWS / 128), 256, 0, stream>>>(
            hbuf, wt_qkv, ROWS, 3 * DIM, DIM, qkvfull, nullptr, nullptr, nullptr);
        attn<<<dim3(SEQ / 128, NHEAD, BATCH), 256, 0, stream>>>(qkvfull, hbuf);
    } else {
        u16* qd = (u16*)d_out;
        for (int c = 0; c < ROWS / CHUNKR; c++) {
            const u16* hA = hbuf + (size_t)c * CHUNKR * DIM;
            gemm_bt<128, 128, 0><<<dim3(3 * DIM / 128, CHUNKR / 128), 256, 0, stream>>>(
                hA, wt_qkv, CHUNKR, 3 * DIM, DIM, qd, nullptr, nullptr, nullptr);
            attn<<<dim3(SEQ / 128, NHEAD, CHUNKB), 256, 0, stream>>>(
                qd, hbuf + (size_t)c * CHUNKR * DIM);
        }
    }

    gemm_bt<128, 64, 1><<<dim3(DIM / 64, ROWS / 128), 256, 0, stream>>>(
        hbuf, wt_proj, ROWS, DIM, DIM, nullptr, out, x, nullptr);

    lnorm<<<ROWS, 256, 0, stream>>>(out, ln2w, ln2b, hbuf);

    gemm_bt<64, 64, 2><<<dim3(HIDDEN / 64, ROWS / 64), 256, 0, stream>>>(
        hbuf, wt_fc1, ROWS, HIDDEN, DIM, gbuf, nullptr, nullptr, bfc1);

    gemm_bt<128, 64, 3><<<dim3(DIM / 64, ROWS / 128), 256, 0, stream>>>(
        gbuf, wt_fc2, ROWS, DIM, HIDDEN, nullptr, out, out, bfc2);
}

// Round 10
// 307.263 us; speedup vs baseline: 1.0433x; 1.0433x over previous
//
#include <hip/hip_runtime.h>
#include <hip/hip_bf16.h>
#include <math.h>

#define DIM 768
#define NHEAD 12
#define HD 64
#define HIDDEN 384
#define BATCH 8
#define SEQ 1024
#define ROWS (BATCH*SEQ)
#define CHUNKB 4
#define CHUNKR (CHUNKB*SEQ)

typedef short bf16x8 __attribute__((ext_vector_type(8)));
typedef float f32x4 __attribute__((ext_vector_type(4)));
typedef unsigned int u32x2 __attribute__((ext_vector_type(2)));
typedef unsigned short u16;
typedef unsigned int u32;

__device__ __forceinline__ u16 f2bs(float f) {
    unsigned int u = __float_as_uint(f);
    unsigned int r = (u + 0x7FFFu + ((u >> 16) & 1u)) >> 16;
    return (u16)r;
}

__device__ __forceinline__ u32 packbf2(float a, float b) {
    __hip_bfloat162 h = __float22bfloat162_rn(make_float2(a, b));
    u32 r;
    __builtin_memcpy(&r, &h, 4);
    return r;
}

// async global->LDS DMA, 16 B/lane; LDS dest = wave-uniform base + lane*16
__device__ __forceinline__ void gld16(const u16* g, u16* l) {
    __builtin_amdgcn_global_load_lds(
        (const __attribute__((address_space(1))) unsigned int*)g,
        (__attribute__((address_space(3))) unsigned int*)l, 16, 0, 0);
}

// ---------------- tiled weight transpose: Wt[n][k] = bf16(W[k][n]) ----------------
__global__ __launch_bounds__(256) void wtrans(const float* __restrict__ W,
                                              u16* __restrict__ Wt, int K, int N) {
    __shared__ float tile[32][33];
    int n0 = blockIdx.x * 32, k0 = blockIdx.y * 32;
    int tx = threadIdx.x & 31, ty = threadIdx.x >> 5;
#pragma unroll
    for (int i = 0; i < 4; i++)
        tile[ty + i * 8][tx] = W[(long)(k0 + ty + i * 8) * N + n0 + tx];
    __syncthreads();
#pragma unroll
    for (int i = 0; i < 4; i++)
        Wt[(long)(n0 + ty + i * 8) * K + k0 + tx] = f2bs(tile[tx][ty + i * 8]);
}

// ---------------- layernorm: fp32 in -> bf16 out, one block per row ----------------
__global__ __launch_bounds__(256) void lnorm(const float* __restrict__ X,
                                             const float* __restrict__ w,
                                             const float* __restrict__ b,
                                             u16* __restrict__ Y) {
    int row = blockIdx.x;
    const float* xr = X + (long)row * DIM;
    int t = threadIdx.x;
    float v0 = xr[t], v1 = xr[t + 256], v2 = xr[t + 512];
    float s = v0 + v1 + v2;
    float s2 = v0 * v0 + v1 * v1 + v2 * v2;
    for (int off = 1; off < 64; off <<= 1) {
        s  += __shfl_xor(s,  off, 64);
        s2 += __shfl_xor(s2, off, 64);
    }
    __shared__ float ss[4], ss2[4];
    int wid = t >> 6;
    if ((t & 63) == 0) { ss[wid] = s; ss2[wid] = s2; }
    __syncthreads();
    s  = ss[0] + ss[1] + ss[2] + ss[3];
    s2 = ss2[0] + ss2[1] + ss2[2] + ss2[3];
    float mu = s * (1.0f / DIM);
    float var = s2 * (1.0f / DIM) - mu * mu;
    float rstd = rsqrtf(var + 1e-5f);
    u16* yr = Y + (long)row * DIM;
    yr[t]       = f2bs((v0 - mu) * rstd * w[t]       + b[t]);
    yr[t + 256] = f2bs((v1 - mu) * rstd * w[t + 256] + b[t + 256]);
    yr[t + 512] = f2bs((v2 - mu) * rstd * w[t + 512] + b[t + 512]);
}

// ---------------- bf16 MFMA GEMM (R7 config: single-buffer, BK=64, gld16+swizzle) -----
template <int BM, int BN, int EPI>
__global__ __launch_bounds__(256) void gemm_bt(const u16* __restrict__ A,
                                               const u16* __restrict__ Bt,
                                               int M, int N, int K,
                                               u16* __restrict__ Cb,
                                               float* __restrict__ Cf,
                                               const float* __restrict__ resid,
                                               const float* __restrict__ bias) {
    constexpr int MB = BM / 32, NB = BN / 32;
    __shared__ u16 As[BM * 64];
    __shared__ u16 Bs[BN * 64];
    int m0 = blockIdx.y * BM;
    int n0 = blockIdx.x * BN;
    int t = threadIdx.x;
    int lane = t & 63, w = t >> 6;
    int quad = lane >> 4, l16 = lane & 15;
    int wr = w >> 1, wc = w & 1;
    int lr = lane >> 3, lc = lane & 7;
    int sc = (lc ^ lr) * 8;      // swizzled source chunk offset (u16)
    int x7 = l16 & 7;

    f32x4 acc[MB][NB];
#pragma unroll
    for (int mb = 0; mb < MB; mb++)
#pragma unroll
        for (int nb = 0; nb < NB; nb++) acc[mb][nb] = (f32x4){0.f, 0.f, 0.f, 0.f};

    for (int kt = 0; kt < K; kt += 64) {
        __syncthreads();
#pragma unroll
        for (int i = 0; i < BM / 32; i++) {
            int rb = i * 32 + w * 8;
            gld16(&A[(long)(m0 + rb + lr) * K + kt + sc], &As[rb * 64]);
        }
#pragma unroll
        for (int i = 0; i < BN / 32; i++) {
            int rb = i * 32 + w * 8;
            gld16(&Bt[(long)(n0 + rb + lr) * K + kt + sc], &Bs[rb * 64]);
        }
        __syncthreads();
#pragma unroll
        for (int kh = 0; kh < 2; kh++) {
            bf16x8 af[MB], bfr[NB];
#pragma unroll
            for (int mb = 0; mb < MB; mb++)
                af[mb] = *(const bf16x8*)&As[(wr * (BM / 2) + mb * 16 + l16) * 64 +
                                             (((kh * 4 + quad) ^ x7) * 8)];
#pragma unroll
            for (int nb = 0; nb < NB; nb++)
                bfr[nb] = *(const bf16x8*)&Bs[(wc * (BN / 2) + nb * 16 + l16) * 64 +
                                              (((kh * 4 + quad) ^ x7) * 8)];
#pragma unroll
            for (int mb = 0; mb < MB; mb++)
#pragma unroll
                for (int nb = 0; nb < NB; nb++)
                    acc[mb][nb] = __builtin_amdgcn_mfma_f32_16x16x32_bf16(af[mb], bfr[nb], acc[mb][nb], 0, 0, 0);
        }
    }

    int mbase = m0 + wr * (BM / 2), nbase = n0 + wc * (BN / 2);
#pragma unroll
    for (int mb = 0; mb < MB; mb++)
#pragma unroll
        for (int nb = 0; nb < NB; nb++) {
            int r0 = mbase + mb * 16 + quad * 4;
            int c = nbase + nb * 16 + l16;
#pragma unroll
            for (int r = 0; r < 4; r++) {
                float v = acc[mb][nb][r];
                long idx = (long)(r0 + r) * N + c;
                if (EPI == 0) {
                    Cb[idx] = f2bs(v);
                } else if (EPI == 1) {
                    Cf[idx] = resid[idx] + v;
                } else if (EPI == 2) {
                    float xg = v + bias[c];
                    Cb[idx] = f2bs(xg * 0.5f * (1.0f + erff(xg * 0.70710678118f)));
                } else {
                    Cf[idx] = resid[idx] + v + bias[c];
                }
            }
        }
}

// ---------------- flash attention: QT=128 q-rows/block, KT=128 keys/iter ----------------
// Grid is (hb=NHEAD*nbatch, qtile=SEQ/128): linear block id = hb + 96*qtile, and 96%8==0,
// so all 8 q-tiles sharing one (h,b)'s K/V land on the SAME XCD -> K/V served by L2
// (R9 counter evidence: q-tile-major grid gave zero L2 sharing, 209 MB HBM/dispatch).
// S^T formulation (per-lane softmax); XOR-swizzled 48 KB LDS (conflict-free, R9-verified).
__global__ __launch_bounds__(256, 3) void attn(const u16* __restrict__ QKV, u16* __restrict__ O) {
    __shared__ u16 Ks[128 * 64];      // 16 KB
    __shared__ u16 Vs[64 * 128];      // 16 KB
    __shared__ u16 Ps[4][16 * 128];   // 16 KB (wave-private rows)
    int h = blockIdx.x % NHEAD;
    int b = blockIdx.x / NHEAD;
    int q0 = blockIdx.y * 128;
    int t = threadIdx.x;
    int lane = t & 63, w = t >> 6;
    int quad = lane >> 4, l16 = lane & 15;

    const long rs = 3 * DIM;  // 2304
    const u16* base = QKV + (long)b * SEQ * rs;

    bf16x8 qf[2][2];
#pragma unroll
    for (int rg = 0; rg < 2; rg++) {
        int qrow = q0 + w * 32 + rg * 16 + l16;
        qf[rg][0] = *(const bf16x8*)&base[(long)qrow * rs + h * 64 + quad * 8];
        qf[rg][1] = *(const bf16x8*)&base[(long)qrow * rs + h * 64 + 32 + quad * 8];
    }

    f32x4 o[2][4];
#pragma unroll
    for (int rg = 0; rg < 2; rg++)
#pragma unroll
        for (int jb = 0; jb < 4; jb++) o[rg][jb] = (f32x4){0.f, 0.f, 0.f, 0.f};
    float m_run[2] = {-1e30f, -1e30f};
    float l_run[2] = {0.f, 0.f};

    const float L2E8 = 11.54156032f;  // 8 * log2(e)

    int kvr = t >> 1;                  // K: row 0..127
    int kcb = (t & 1) * 4;             // K: chunk base (4 chunks of 8 u16 each)
    int kx7 = kvr & 7;                 // K write swizzle mask
    int vp = t & 63, vo = t >> 6;      // V: kv-pair, d-block
    int vc = vp >> 2, voff = (vp & 3) * 2;

    const u16* kptr = &base[(long)kvr * rs + DIM + h * 64 + kcb * 8];
    const u16* vptr = &base[(long)(2 * vp) * rs + 2 * DIM + h * 64 + vo * 16];
    const long kstep = (long)128 * rs;

    bf16x8 kpre[4], va0, va1, vb0, vb1;
    kpre[0] = *(const bf16x8*)&kptr[0];
    kpre[1] = *(const bf16x8*)&kptr[8];
    kpre[2] = *(const bf16x8*)&kptr[16];
    kpre[3] = *(const bf16x8*)&kptr[24];
    va0 = *(const bf16x8*)&vptr[0];
    va1 = *(const bf16x8*)&vptr[8];
    vb0 = *(const bf16x8*)&vptr[rs];
    vb1 = *(const bf16x8*)&vptr[rs + 8];

    for (int kt = 0; kt < SEQ; kt += 128) {
        __syncthreads();
        {
#pragma unroll
            for (int j = 0; j < 4; j++)
                *(bf16x8*)&Ks[kvr * 64 + (((kcb + j) ^ kx7) * 8)] = kpre[j];
#pragma unroll
            for (int j = 0; j < 8; j++) {
                int d = vo * 16 + j;
                u32 pk = (u32)(u16)va0[j] | ((u32)(u16)vb0[j] << 16);
                *(u32*)&Vs[d * 128 + ((vc ^ j) * 8) + voff] = pk;
            }
#pragma unroll
            for (int j = 0; j < 8; j++) {
                int d = vo * 16 + 8 + j;
                u32 pk = (u32)(u16)va1[j] | ((u32)(u16)vb1[j] << 16);
                *(u32*)&Vs[d * 128 + ((vc ^ (8 + j)) * 8) + voff] = pk;
            }
        }
        __syncthreads();

        if (kt + 128 < SEQ) {
            kptr += kstep; vptr += kstep;
            kpre[0] = *(const bf16x8*)&kptr[0];
            kpre[1] = *(const bf16x8*)&kptr[8];
            kpre[2] = *(const bf16x8*)&kptr[16];
            kpre[3] = *(const bf16x8*)&kptr[24];
            va0 = *(const bf16x8*)&vptr[0];
            va1 = *(const bf16x8*)&vptr[8];
            vb0 = *(const bf16x8*)&vptr[rs];
            vb1 = *(const bf16x8*)&vptr[rs + 8];
        }

#pragma unroll
        for (int rg = 0; rg < 2; rg++) {
            f32x4 s[8];
#pragma unroll
            for (int jb = 0; jb < 8; jb++) {
                int krow = jb * 16 + l16;
                int m7 = l16 & 7;   // == krow&7
                bf16x8 kf0 = *(const bf16x8*)&Ks[krow * 64 + ((quad ^ m7) * 8)];
                bf16x8 kf1 = *(const bf16x8*)&Ks[krow * 64 + (((4 + quad) ^ m7) * 8)];
                f32x4 z = (f32x4){0.f, 0.f, 0.f, 0.f};
                z = __builtin_amdgcn_mfma_f32_16x16x32_bf16(kf0, qf[rg][0], z, 0, 0, 0);
                z = __builtin_amdgcn_mfma_f32_16x16x32_bf16(kf1, qf[rg][1], z, 0, 0, 0);
                s[jb] = z;
            }

            float m1 = s[0][0];
#pragma unroll
            for (int jb = 0; jb < 8; jb++)
#pragma unroll
                for (int r = 0; r < 4; r++) m1 = fmaxf(m1, s[jb][r]);
            m1 = fmaxf(m1, __shfl_xor(m1, 16, 64));
            m1 = fmaxf(m1, __shfl_xor(m1, 32, 64));
            float mn = fmaxf(m_run[rg], m1);
            float alpha = exp2f((m_run[rg] - mn) * L2E8);
            m_run[rg] = mn;
            float mn8 = mn * L2E8;
            float rsum = 0.f;
#pragma unroll
            for (int jb = 0; jb < 8; jb++)
#pragma unroll
                for (int r = 0; r < 4; r++) {
                    float p = exp2f(fmaf(s[jb][r], L2E8, -mn8));
                    s[jb][r] = p;
                    rsum += p;
                }
            rsum += __shfl_xor(rsum, 16, 64);
            rsum += __shfl_xor(rsum, 32, 64);
            l_run[rg] = l_run[rg] * alpha + rsum;

            float a0 = __shfl(alpha, quad * 4 + 0, 16);
            float a1 = __shfl(alpha, quad * 4 + 1, 16);
            float a2 = __shfl(alpha, quad * 4 + 2, 16);
            float a3 = __shfl(alpha, quad * 4 + 3, 16);
#pragma unroll
            for (int jb = 0; jb < 4; jb++) {
                o[rg][jb][0] *= a0; o[rg][jb][1] *= a1;
                o[rg][jb][2] *= a2; o[rg][jb][3] *= a3;
            }

#pragma unroll
            for (int jb = 0; jb < 8; jb++) {
                u32x2 pk;
                pk.x = packbf2(s[jb][0], s[jb][1]);
                pk.y = packbf2(s[jb][2], s[jb][3]);
                int swc = (jb * 2 + (quad >> 1)) ^ l16;
                *(u32x2*)&Ps[w][l16 * 128 + swc * 8 + (quad & 1) * 4] = pk;
            }

#pragma unroll
            for (int c = 0; c < 4; c++) {
                bf16x8 pf = *(const bf16x8*)&Ps[w][l16 * 128 + (((c * 4 + quad) ^ l16) * 8)];
#pragma unroll
                for (int jb = 0; jb < 4; jb++) {
                    int d = jb * 16 + l16;
                    bf16x8 vf = *(const bf16x8*)&Vs[d * 128 + (((c * 4 + quad) ^ l16) * 8)];
                    o[rg][jb] = __builtin_amdgcn_mfma_f32_16x16x32_bf16(pf, vf, o[rg][jb], 0, 0, 0);
                }
            }
        }
    }

#pragma unroll
    for (int rg = 0; rg < 2; rg++) {
        float l0 = __shfl(l_run[rg], quad * 4 + 0, 16);
        float l1 = __shfl(l_run[rg], quad * 4 + 1, 16);
        float l2 = __shfl(l_run[rg], quad * 4 + 2, 16);
        float l3 = __shfl(l_run[rg], quad * 4 + 3, 16);
        u16* orow = O + ((long)(b * SEQ + q0 + w * 32 + rg * 16)) * DIM + h * 64;
#pragma unroll
        for (int jb = 0; jb < 4; jb++) {
            u32 p01 = packbf2(o[rg][jb][0] / l0, o[rg][jb][1] / l1);
            u32 p23 = packbf2(o[rg][jb][2] / l2, o[rg][jb][3] / l3);
            int cidx = jb * 16 + l16;
            orow[(long)(quad * 4 + 0) * DIM + cidx] = (u16)p01;
            orow[(long)(quad * 4 + 1) * DIM + cidx] = (u16)(p01 >> 16);
            orow[(long)(quad * 4 + 2) * DIM + cidx] = (u16)p23;
            orow[(long)(quad * 4 + 3) * DIM + cidx] = (u16)(p23 >> 16);
        }
    }
}

extern "C" void kernel_launch(void* const* d_in, const int* in_sizes, int n_in,
                              void* d_out, int out_size, void* d_ws, size_t ws_size,
                              hipStream_t stream) {
    const float* x     = (const float*)d_in[0];
    const float* ln1w  = (const float*)d_in[1];
    const float* ln1b  = (const float*)d_in[2];
    const float* ln2w  = (const float*)d_in[3];
    const float* ln2b  = (const float*)d_in[4];
    const float* wqkv  = (const float*)d_in[5];
    const float* wproj = (const float*)d_in[6];
    const float* wfc1  = (const float*)d_in[7];
    const float* bfc1  = (const float*)d_in[8];
    const float* wfc2  = (const float*)d_in[9];
    const float* bfc2  = (const float*)d_in[10];
    float* out = (float*)d_out;

    char* ws = (char*)d_ws;
    size_t off = 0;
    auto alloc = [&](size_t bytes) {
        void* p = ws + off;
        off = (off + bytes + 255) & ~(size_t)255;
        return p;
    };
    u16* wt_qkv  = (u16*)alloc((size_t)3 * DIM * DIM * 2);
    u16* wt_proj = (u16*)alloc((size_t)DIM * DIM * 2);
    u16* wt_fc1  = (u16*)alloc((size_t)HIDDEN * DIM * 2);
    u16* wt_fc2  = (u16*)alloc((size_t)DIM * HIDDEN * 2);
    u16* hbuf    = (u16*)alloc((size_t)ROWS * DIM * 2);
    u16* gbuf    = (u16*)alloc((size_t)ROWS * HIDDEN * 2);
    size_t qkv_bytes = (size_t)ROWS * 3 * DIM * 2;
    u16* qkvfull = (off + qkv_bytes + 1024 <= ws_size) ? (u16*)alloc(qkv_bytes) : nullptr;

    wtrans<<<dim3(3 * DIM / 32, DIM / 32), 256, 0, stream>>>(wqkv, wt_qkv, DIM, 3 * DIM);
    wtrans<<<dim3(DIM / 32, DIM / 32), 256, 0, stream>>>(wproj, wt_proj, DIM, DIM);
    wtrans<<<dim3(HIDDEN / 32, DIM / 32), 256, 0, stream>>>(wfc1, wt_fc1, DIM, HIDDEN);
    wtrans<<<dim3(DIM / 32, HIDDEN / 32), 256, 0, stream>>>(wfc2, wt_fc2, HIDDEN, DIM);

    lnorm<<<ROWS, 256, 0, stream>>>(x, ln1w, ln1b, hbuf);

    if (qkvfull) {
        gemm_bt<128, 128, 0><<<dim3(3 * DIM / 128, ROWS / 128), 256, 0, stream>>>(
            hbuf, wt_qkv, ROWS, 3 * DIM, DIM, qkvfull, nullptr, nullptr, nullptr);
        attn<<<dim3(NHEAD * BATCH, SEQ / 128), 256, 0, stream>>>(qkvfull, hbuf);
    } else {
        u16* qd = (u16*)d_out;
        for (int c = 0; c < ROWS / CHUNKR; c++) {
            const u16* hA = hbuf + (size_t)c * CHUNKR * DIM;
            gemm_bt<128, 128, 0><<<dim3(3 * DIM / 128, CHUNKR / 128), 256, 0, stream>>>(
                hA, wt_qkv, CHUNKR, 3 * DIM, DIM, qd, nullptr, nullptr, nullptr);
            attn<<<dim3(NHEAD * CHUNKB, SEQ / 128), 256, 0, stream>>>(
                qd, hbuf + (size_t)c * CHUNKR * DIM);
        }
    }

    gemm_bt<128, 64, 1><<<dim3(DIM / 64, ROWS / 128), 256, 0, stream>>>(
        hbuf, wt_proj, ROWS, DIM, DIM, nullptr, out, x, nullptr);

    lnorm<<<ROWS, 256, 0, stream>>>(out, ln2w, ln2b, hbuf);

    gemm_bt<64, 64, 2><<<dim3(HIDDEN / 64, ROWS / 64), 256, 0, stream>>>(
        hbuf, wt_fc1, ROWS, HIDDEN, DIM, gbuf, nullptr, nullptr, bfc1);

    gemm_bt<128, 64, 3><<<dim3(DIM / 64, ROWS / 128), 256, 0, stream>>>(
        gbuf, wt_fc2, ROWS, DIM, HIDDEN, nullptr, out, out, bfc2);
}

// Round 11
// 283.108 us; speedup vs baseline: 1.1323x; 1.0853x over previous
//
#include <hip/hip_runtime.h>
#include <hip/hip_bf16.h>
#include <math.h>

#define DIM 768
#define NHEAD 12
#define HD 64
#define HIDDEN 384
#define BATCH 8
#define SEQ 1024
#define ROWS (BATCH*SEQ)
#define CHUNKB 4
#define CHUNKR (CHUNKB*SEQ)

typedef short bf16x8 __attribute__((ext_vector_type(8)));
typedef float f32x4 __attribute__((ext_vector_type(4)));
typedef unsigned int u32x2 __attribute__((ext_vector_type(2)));
typedef unsigned short u16;
typedef unsigned int u32;

__device__ __forceinline__ u16 f2bs(float f) {
    unsigned int u = __float_as_uint(f);
    unsigned int r = (u + 0x7FFFu + ((u >> 16) & 1u)) >> 16;
    return (u16)r;
}

__device__ __forceinline__ u32 packbf2(float a, float b) {
    __hip_bfloat162 h = __float22bfloat162_rn(make_float2(a, b));
    u32 r;
    __builtin_memcpy(&r, &h, 4);
    return r;
}

// async global->LDS DMA, 16 B/lane; LDS dest = wave-uniform base + lane*16
__device__ __forceinline__ void gld16(const u16* g, u16* l) {
    __builtin_amdgcn_global_load_lds(
        (const __attribute__((address_space(1))) unsigned int*)g,
        (__attribute__((address_space(3))) unsigned int*)l, 16, 0, 0);
}

// ---------------- tiled weight transpose: Wt[n][k] = bf16(W[k][n]) ----------------
__global__ __launch_bounds__(256) void wtrans(const float* __restrict__ W,
                                              u16* __restrict__ Wt, int K, int N) {
    __shared__ float tile[32][33];
    int n0 = blockIdx.x * 32, k0 = blockIdx.y * 32;
    int tx = threadIdx.x & 31, ty = threadIdx.x >> 5;
#pragma unroll
    for (int i = 0; i < 4; i++)
        tile[ty + i * 8][tx] = W[(long)(k0 + ty + i * 8) * N + n0 + tx];
    __syncthreads();
#pragma unroll
    for (int i = 0; i < 4; i++)
        Wt[(long)(n0 + ty + i * 8) * K + k0 + tx] = f2bs(tile[tx][ty + i * 8]);
}

// ---------------- layernorm: fp32 in -> bf16 out, one block per row ----------------
__global__ __launch_bounds__(256) void lnorm(const float* __restrict__ X,
                                             const float* __restrict__ w,
                                             const float* __restrict__ b,
                                             u16* __restrict__ Y) {
    int row = blockIdx.x;
    const float* xr = X + (long)row * DIM;
    int t = threadIdx.x;
    float v0 = xr[t], v1 = xr[t + 256], v2 = xr[t + 512];
    float s = v0 + v1 + v2;
    float s2 = v0 * v0 + v1 * v1 + v2 * v2;
    for (int off = 1; off < 64; off <<= 1) {
        s  += __shfl_xor(s,  off, 64);
        s2 += __shfl_xor(s2, off, 64);
    }
    __shared__ float ss[4], ss2[4];
    int wid = t >> 6;
    if ((t & 63) == 0) { ss[wid] = s; ss2[wid] = s2; }
    __syncthreads();
    s  = ss[0] + ss[1] + ss[2] + ss[3];
    s2 = ss2[0] + ss2[1] + ss2[2] + ss2[3];
    float mu = s * (1.0f / DIM);
    float var = s2 * (1.0f / DIM) - mu * mu;
    float rstd = rsqrtf(var + 1e-5f);
    u16* yr = Y + (long)row * DIM;
    yr[t]       = f2bs((v0 - mu) * rstd * w[t]       + b[t]);
    yr[t + 256] = f2bs((v1 - mu) * rstd * w[t + 256] + b[t + 256]);
    yr[t + 512] = f2bs((v2 - mu) * rstd * w[t + 512] + b[t + 512]);
}

// ---------------- bf16 MFMA GEMM (single-buffer, BK=64, gld16+swizzle) ----------------
// Grid is (m-tile, n-tile): blocks sharing one A-panel get ids differing by gridDim.x
// (multiple of 8) -> same XCD -> A served from that XCD's L2; B fits in L2 (<=3.5 MB).
template <int BM, int BN, int EPI>
__global__ __launch_bounds__(256) void gemm_bt(const u16* __restrict__ A,
                                               const u16* __restrict__ Bt,
                                               int M, int N, int K,
                                               u16* __restrict__ Cb,
                                               float* __restrict__ Cf,
                                               const float* __restrict__ resid,
                                               const float* __restrict__ bias) {
    constexpr int MB = BM / 32, NB = BN / 32;
    __shared__ u16 As[BM * 64];
    __shared__ u16 Bs[BN * 64];
    int m0 = blockIdx.x * BM;     // m-major grid (XCD locality for A)
    int n0 = blockIdx.y * BN;
    int t = threadIdx.x;
    int lane = t & 63, w = t >> 6;
    int quad = lane >> 4, l16 = lane & 15;
    int wr = w >> 1, wc = w & 1;
    int lr = lane >> 3, lc = lane & 7;
    int sc = (lc ^ lr) * 8;      // swizzled source chunk offset (u16)
    int x7 = l16 & 7;

    f32x4 acc[MB][NB];
#pragma unroll
    for (int mb = 0; mb < MB; mb++)
#pragma unroll
        for (int nb = 0; nb < NB; nb++) acc[mb][nb] = (f32x4){0.f, 0.f, 0.f, 0.f};

    for (int kt = 0; kt < K; kt += 64) {
        __syncthreads();
#pragma unroll
        for (int i = 0; i < BM / 32; i++) {
            int rb = i * 32 + w * 8;
            gld16(&A[(long)(m0 + rb + lr) * K + kt + sc], &As[rb * 64]);
        }
#pragma unroll
        for (int i = 0; i < BN / 32; i++) {
            int rb = i * 32 + w * 8;
            gld16(&Bt[(long)(n0 + rb + lr) * K + kt + sc], &Bs[rb * 64]);
        }
        __syncthreads();
#pragma unroll
        for (int kh = 0; kh < 2; kh++) {
            bf16x8 af[MB], bfr[NB];
#pragma unroll
            for (int mb = 0; mb < MB; mb++)
                af[mb] = *(const bf16x8*)&As[(wr * (BM / 2) + mb * 16 + l16) * 64 +
                                             (((kh * 4 + quad) ^ x7) * 8)];
#pragma unroll
            for (int nb = 0; nb < NB; nb++)
                bfr[nb] = *(const bf16x8*)&Bs[(wc * (BN / 2) + nb * 16 + l16) * 64 +
                                              (((kh * 4 + quad) ^ x7) * 8)];
#pragma unroll
            for (int mb = 0; mb < MB; mb++)
#pragma unroll
                for (int nb = 0; nb < NB; nb++)
                    acc[mb][nb] = __builtin_amdgcn_mfma_f32_16x16x32_bf16(af[mb], bfr[nb], acc[mb][nb], 0, 0, 0);
        }
    }

    int mbase = m0 + wr * (BM / 2), nbase = n0 + wc * (BN / 2);
#pragma unroll
    for (int mb = 0; mb < MB; mb++)
#pragma unroll
        for (int nb = 0; nb < NB; nb++) {
            int r0 = mbase + mb * 16 + quad * 4;
            int c = nbase + nb * 16 + l16;
#pragma unroll
            for (int r = 0; r < 4; r++) {
                float v = acc[mb][nb][r];
                long idx = (long)(r0 + r) * N + c;
                if (EPI == 0) {
                    Cb[idx] = f2bs(v);
                } else if (EPI == 1) {
                    Cf[idx] = resid[idx] + v;
                } else if (EPI == 2) {
                    float xg = v + bias[c];
                    Cb[idx] = f2bs(xg * 0.5f * (1.0f + erff(xg * 0.70710678118f)));
                } else {
                    Cf[idx] = resid[idx] + v + bias[c];
                }
            }
        }
}

// ---------------- flash attention: QT=128 q-rows/block, KT=128 keys/iter ----------------
// Grid (b, h*qtile): linear id = b + 8*y -> XCD = b. The whole batch (all heads, all
// q-tiles) lives on ONE XCD: K/V row window shared across heads in L2 AND the O rows are
// fully assembled in the same L2 before eviction (R10 evidence: h-major grid gave 3.6x
// O-write amplification 45 MB; R7's same-XCD-rows gave 15 MB).
// S^T formulation (per-lane softmax); XOR-swizzled 48 KB LDS (conflict-free, R9-verified).
__global__ __launch_bounds__(256, 3) void attn(const u16* __restrict__ QKV, u16* __restrict__ O) {
    __shared__ u16 Ks[128 * 64];      // 16 KB
    __shared__ u16 Vs[64 * 128];      // 16 KB
    __shared__ u16 Ps[4][16 * 128];   // 16 KB (wave-private rows)
    int b = blockIdx.x;
    int h = blockIdx.y % NHEAD;
    int q0 = (blockIdx.y / NHEAD) * 128;
    int t = threadIdx.x;
    int lane = t & 63, w = t >> 6;
    int quad = lane >> 4, l16 = lane & 15;

    const long rs = 3 * DIM;  // 2304
    const u16* base = QKV + (long)b * SEQ * rs;

    bf16x8 qf[2][2];
#pragma unroll
    for (int rg = 0; rg < 2; rg++) {
        int qrow = q0 + w * 32 + rg * 16 + l16;
        qf[rg][0] = *(const bf16x8*)&base[(long)qrow * rs + h * 64 + quad * 8];
        qf[rg][1] = *(const bf16x8*)&base[(long)qrow * rs + h * 64 + 32 + quad * 8];
    }

    f32x4 o[2][4];
#pragma unroll
    for (int rg = 0; rg < 2; rg++)
#pragma unroll
        for (int jb = 0; jb < 4; jb++) o[rg][jb] = (f32x4){0.f, 0.f, 0.f, 0.f};
    float m_run[2] = {-1e30f, -1e30f};
    float l_run[2] = {0.f, 0.f};

    const float L2E8 = 11.54156032f;  // 8 * log2(e)

    int kvr = t >> 1;                  // K: row 0..127
    int kcb = (t & 1) * 4;             // K: chunk base (4 chunks of 8 u16 each)
    int kx7 = kvr & 7;                 // K write swizzle mask
    int vp = t & 63, vo = t >> 6;      // V: kv-pair, d-block
    int vc = vp >> 2, voff = (vp & 3) * 2;

    const u16* kptr = &base[(long)kvr * rs + DIM + h * 64 + kcb * 8];
    const u16* vptr = &base[(long)(2 * vp) * rs + 2 * DIM + h * 64 + vo * 16];
    const long kstep = (long)128 * rs;

    bf16x8 kpre[4], va0, va1, vb0, vb1;
    kpre[0] = *(const bf16x8*)&kptr[0];
    kpre[1] = *(const bf16x8*)&kptr[8];
    kpre[2] = *(const bf16x8*)&kptr[16];
    kpre[3] = *(const bf16x8*)&kptr[24];
    va0 = *(const bf16x8*)&vptr[0];
    va1 = *(const bf16x8*)&vptr[8];
    vb0 = *(const bf16x8*)&vptr[rs];
    vb1 = *(const bf16x8*)&vptr[rs + 8];

    for (int kt = 0; kt < SEQ; kt += 128) {
        __syncthreads();
        {
#pragma unroll
            for (int j = 0; j < 4; j++)
                *(bf16x8*)&Ks[kvr * 64 + (((kcb + j) ^ kx7) * 8)] = kpre[j];
#pragma unroll
            for (int j = 0; j < 8; j++) {
                int d = vo * 16 + j;
                u32 pk = (u32)(u16)va0[j] | ((u32)(u16)vb0[j] << 16);
                *(u32*)&Vs[d * 128 + ((vc ^ j) * 8) + voff] = pk;
            }
#pragma unroll
            for (int j = 0; j < 8; j++) {
                int d = vo * 16 + 8 + j;
                u32 pk = (u32)(u16)va1[j] | ((u32)(u16)vb1[j] << 16);
                *(u32*)&Vs[d * 128 + ((vc ^ (8 + j)) * 8) + voff] = pk;
            }
        }
        __syncthreads();

        if (kt + 128 < SEQ) {
            kptr += kstep; vptr += kstep;
            kpre[0] = *(const bf16x8*)&kptr[0];
            kpre[1] = *(const bf16x8*)&kptr[8];
            kpre[2] = *(const bf16x8*)&kptr[16];
            kpre[3] = *(const bf16x8*)&kptr[24];
            va0 = *(const bf16x8*)&vptr[0];
            va1 = *(const bf16x8*)&vptr[8];
            vb0 = *(const bf16x8*)&vptr[rs];
            vb1 = *(const bf16x8*)&vptr[rs + 8];
        }

#pragma unroll
        for (int rg = 0; rg < 2; rg++) {
            f32x4 s[8];
#pragma unroll
            for (int jb = 0; jb < 8; jb++) {
                int krow = jb * 16 + l16;
                int m7 = l16 & 7;   // == krow&7
                bf16x8 kf0 = *(const bf16x8*)&Ks[krow * 64 + ((quad ^ m7) * 8)];
                bf16x8 kf1 = *(const bf16x8*)&Ks[krow * 64 + (((4 + quad) ^ m7) * 8)];
                f32x4 z = (f32x4){0.f, 0.f, 0.f, 0.f};
                z = __builtin_amdgcn_mfma_f32_16x16x32_bf16(kf0, qf[rg][0], z, 0, 0, 0);
                z = __builtin_amdgcn_mfma_f32_16x16x32_bf16(kf1, qf[rg][1], z, 0, 0, 0);
                s[jb] = z;
            }

            float m1 = s[0][0];
#pragma unroll
            for (int jb = 0; jb < 8; jb++)
#pragma unroll
                for (int r = 0; r < 4; r++) m1 = fmaxf(m1, s[jb][r]);
            m1 = fmaxf(m1, __shfl_xor(m1, 16, 64));
            m1 = fmaxf(m1, __shfl_xor(m1, 32, 64));
            float mn = fmaxf(m_run[rg], m1);
            float alpha = exp2f((m_run[rg] - mn) * L2E8);
            m_run[rg] = mn;
            float mn8 = mn * L2E8;
            float rsum = 0.f;
#pragma unroll
            for (int jb = 0; jb < 8; jb++)
#pragma unroll
                for (int r = 0; r < 4; r++) {
                    float p = exp2f(fmaf(s[jb][r], L2E8, -mn8));
                    s[jb][r] = p;
                    rsum += p;
                }
            rsum += __shfl_xor(rsum, 16, 64);
            rsum += __shfl_xor(rsum, 32, 64);
            l_run[rg] = l_run[rg] * alpha + rsum;

            float a0 = __shfl(alpha, quad * 4 + 0, 16);
            float a1 = __shfl(alpha, quad * 4 + 1, 16);
            float a2 = __shfl(alpha, quad * 4 + 2, 16);
            float a3 = __shfl(alpha, quad * 4 + 3, 16);
#pragma unroll
            for (int jb = 0; jb < 4; jb++) {
                o[rg][jb][0] *= a0; o[rg][jb][1] *= a1;
                o[rg][jb][2] *= a2; o[rg][jb][3] *= a3;
            }

#pragma unroll
            for (int jb = 0; jb < 8; jb++) {
                u32x2 pk;
                pk.x = packbf2(s[jb][0], s[jb][1]);
                pk.y = packbf2(s[jb][2], s[jb][3]);
                int swc = (jb * 2 + (quad >> 1)) ^ l16;
                *(u32x2*)&Ps[w][l16 * 128 + swc * 8 + (quad & 1) * 4] = pk;
            }

#pragma unroll
            for (int c = 0; c < 4; c++) {
                bf16x8 pf = *(const bf16x8*)&Ps[w][l16 * 128 + (((c * 4 + quad) ^ l16) * 8)];
#pragma unroll
                for (int jb = 0; jb < 4; jb++) {
                    int d = jb * 16 + l16;
                    bf16x8 vf = *(const bf16x8*)&Vs[d * 128 + (((c * 4 + quad) ^ l16) * 8)];
                    o[rg][jb] = __builtin_amdgcn_mfma_f32_16x16x32_bf16(pf, vf, o[rg][jb], 0, 0, 0);
                }
            }
        }
    }

#pragma unroll
    for (int rg = 0; rg < 2; rg++) {
        float l0 = __shfl(l_run[rg], quad * 4 + 0, 16);
        float l1 = __shfl(l_run[rg], quad * 4 + 1, 16);
        float l2 = __shfl(l_run[rg], quad * 4 + 2, 16);
        float l3 = __shfl(l_run[rg], quad * 4 + 3, 16);
        u16* orow = O + ((long)(b * SEQ + q0 + w * 32 + rg * 16)) * DIM + h * 64;
#pragma unroll
        for (int jb = 0; jb < 4; jb++) {
            u32 p01 = packbf2(o[rg][jb][0] / l0, o[rg][jb][1] / l1);
            u32 p23 = packbf2(o[rg][jb][2] / l2, o[rg][jb][3] / l3);
            int cidx = jb * 16 + l16;
            orow[(long)(quad * 4 + 0) * DIM + cidx] = (u16)p01;
            orow[(long)(quad * 4 + 1) * DIM + cidx] = (u16)(p01 >> 16);
            orow[(long)(quad * 4 + 2) * DIM + cidx] = (u16)p23;
            orow[(long)(quad * 4 + 3) * DIM + cidx] = (u16)(p23 >> 16);
        }
    }
}

extern "C" void kernel_launch(void* const* d_in, const int* in_sizes, int n_in,
                              void* d_out, int out_size, void* d_ws, size_t ws_size,
                              hipStream_t stream) {
    const float* x     = (const float*)d_in[0];
    const float* ln1w  = (const float*)d_in[1];
    const float* ln1b  = (const float*)d_in[2];
    const float* ln2w  = (const float*)d_in[3];
    const float* ln2b  = (const float*)d_in[4];
    const float* wqkv  = (const float*)d_in[5];
    const float* wproj = (const float*)d_in[6];
    const float* wfc1  = (const float*)d_in[7];
    const float* bfc1  = (const float*)d_in[8];
    const float* wfc2  = (const float*)d_in[9];
    const float* bfc2  = (const float*)d_in[10];
    float* out = (float*)d_out;

    char* ws = (char*)d_ws;
    size_t off = 0;
    auto alloc = [&](size_t bytes) {
        void* p = ws + off;
        off = (off + bytes + 255) & ~(size_t)255;
        return p;
    };
    u16* wt_qkv  = (u16*)alloc((size_t)3 * DIM * DIM * 2);
    u16* wt_proj = (u16*)alloc((size_t)DIM * DIM * 2);
    u16* wt_fc1  = (u16*)alloc((size_t)HIDDEN * DIM * 2);
    u16* wt_fc2  = (u16*)alloc((size_t)DIM * HIDDEN * 2);
    u16* hbuf    = (u16*)alloc((size_t)ROWS * DIM * 2);
    u16* gbuf    = (u16*)alloc((size_t)ROWS * HIDDEN * 2);
    size_t qkv_bytes = (size_t)ROWS * 3 * DIM * 2;
    u16* qkvfull = (off + qkv_bytes + 1024 <= ws_size) ? (u16*)alloc(qkv_bytes) : nullptr;

    wtrans<<<dim3(3 * DIM / 32, DIM / 32), 256, 0, stream>>>(wqkv, wt_qkv, DIM, 3 * DIM);
    wtrans<<<dim3(DIM / 32, DIM / 32), 256, 0, stream>>>(wproj, wt_proj, DIM, DIM);
    wtrans<<<dim3(HIDDEN / 32, DIM / 32), 256, 0, stream>>>(wfc1, wt_fc1, DIM, HIDDEN);
    wtrans<<<dim3(DIM / 32, HIDDEN / 32), 256, 0, stream>>>(wfc2, wt_fc2, HIDDEN, DIM);

    lnorm<<<ROWS, 256, 0, stream>>>(x, ln1w, ln1b, hbuf);

    if (qkvfull) {
        gemm_bt<128, 128, 0><<<dim3(ROWS / 128, 3 * DIM / 128), 256, 0, stream>>>(
            hbuf, wt_qkv, ROWS, 3 * DIM, DIM, qkvfull, nullptr, nullptr, nullptr);
        attn<<<dim3(BATCH, NHEAD * (SEQ / 128)), 256, 0, stream>>>(qkvfull, hbuf);
    } else {
        u16* qd = (u16*)d_out;
        for (int c = 0; c < ROWS / CHUNKR; c++) {
            const u16* hA = hbuf + (size_t)c * CHUNKR * DIM;
            gemm_bt<128, 128, 0><<<dim3(CHUNKR / 128, 3 * DIM / 128), 256, 0, stream>>>(
                hA, wt_qkv, CHUNKR, 3 * DIM, DIM, qd, nullptr, nullptr, nullptr);
            attn<<<dim3(CHUNKB, NHEAD * (SEQ / 128)), 256, 0, stream>>>(
                qd, hbuf + (size_t)c * CHUNKR * DIM);
        }
    }

    gemm_bt<128, 64, 1><<<dim3(ROWS / 128, DIM / 64), 256, 0, stream>>>(
        hbuf, wt_proj, ROWS, DIM, DIM, nullptr, out, x, nullptr);

    lnorm<<<ROWS, 256, 0, stream>>>(out, ln2w, ln2b, hbuf);

    gemm_bt<64, 64, 2><<<dim3(ROWS / 64, HIDDEN / 64), 256, 0, stream>>>(
        hbuf, wt_fc1, ROWS, HIDDEN, DIM, gbuf, nullptr, nullptr, bfc1);

    gemm_bt<128, 64, 3><<<dim3(ROWS / 128, DIM / 64), 256, 0, stream>>>(
        gbuf, wt_fc2, ROWS, DIM, HIDDEN, nullptr, out, out, bfc2);
}